// Round 1
// 1124.487 us; speedup vs baseline: 1.3121x; 1.3121x over previous
//
#include <hip/hip_runtime.h>
#include <hip/hip_bf16.h>

#define M_TOK 8192
#define K_IN  4096
#define N_OUT 11008

typedef __bf16 bf16x8 __attribute__((ext_vector_type(8)));
typedef float  f32x4  __attribute__((ext_vector_type(4)));
typedef unsigned short u16x8 __attribute__((ext_vector_type(8)));

__device__ __forceinline__ unsigned short f2bf_rne(float f) {
  unsigned int u = __float_as_uint(f);
  u += 0x7FFFu + ((u >> 16) & 1u);   // round-to-nearest-even
  return (unsigned short)(u >> 16);
}

// ---- conversion kernels (memory-bound): 32B load / 16B store per lane ----
__global__ __launch_bounds__(256) void cvt_f32_to_bf16(
    const float4* __restrict__ in, u16x8* __restrict__ out, int n8) {
  int i = blockIdx.x * blockDim.x + threadIdx.x;
  if (i >= n8) return;
  float4 a = in[2 * i], b = in[2 * i + 1];
  u16x8 o;
  o[0] = f2bf_rne(a.x); o[1] = f2bf_rne(a.y); o[2] = f2bf_rne(a.z); o[3] = f2bf_rne(a.w);
  o[4] = f2bf_rne(b.x); o[5] = f2bf_rne(b.y); o[6] = f2bf_rne(b.z); o[7] = f2bf_rne(b.w);
  out[i] = o;
}

__global__ __launch_bounds__(256) void cvt_i32_to_bf16(
    const int4* __restrict__ in, u16x8* __restrict__ out, int n8) {
  int i = blockIdx.x * blockDim.x + threadIdx.x;
  if (i >= n8) return;
  int4 a = in[2 * i], b = in[2 * i + 1];
  u16x8 o;  // values {0,1,2} -> exact in bf16
  o[0] = f2bf_rne((float)a.x); o[1] = f2bf_rne((float)a.y);
  o[2] = f2bf_rne((float)a.z); o[3] = f2bf_rne((float)a.w);
  o[4] = f2bf_rne((float)b.x); o[5] = f2bf_rne((float)b.y);
  o[6] = f2bf_rne((float)b.z); o[7] = f2bf_rne((float)b.w);
  out[i] = o;
}

// ============================================================================
// 256x256 8-phase bf16 NT GEMM (T1 XCD-swizzle + T2 LDS XOR-swizzle +
// T3/T4 8-phase counted-vmcnt + T5 setprio), per cdna_hip_programming.md §5.
// C[t][o] = sum_k A[t][k]*B[o][k]; epilogue *scale[o]+bias[o].
//
// Geometry: BM=BN=256, BK=64, 512 thr = 8 waves (2M x 4N), wave tile 128x64,
// acc[8][4] f32x4. LDS 128 KiB dynamic:
//   A: [buf:2][half:2][128][64]bf16 at  buf*32768 + half*16384
//   B: same + 65536.
// Swizzle (involution, 16B-granular): byte_col ^= (row&7)<<4.
//   - global_load_lds dest is LINEAR; the global SOURCE k-offset is
//     pre-swizzled (rule 21), ds_read applies the same XOR.
// Staging: half-tile = 128 rows x 64 cols = 16KB = 2 loads/thread (16B each).
//   Per phase 1 half-tile staged; target region's last reader finished >=1
//   phase earlier (race-free via the lgkmcnt(0)-before-barrier discipline).
// vmcnt(6) at P4/P8 only: at each wait 7 half-tiles (14 loads) outstanding,
//   oldest 4 = the next buffer's K-tile, 3 half-tiles stay in flight.
// ============================================================================

#define GL16(gp, loff)                                                      \
  __builtin_amdgcn_global_load_lds(                                        \
      (const __attribute__((address_space(1))) void*)(gp),                 \
      (__attribute__((address_space(3))) void*)(ldsc + (loff)), 16, 0, 0)

#define STAGE_A(tile, h, buf) do {                                          \
  GL16(aptr##h + (tile) * 64,            (buf)*32768 + (h)*16384 + tid*16); \
  GL16(aptr##h + 64*K_IN + (tile) * 64,  (buf)*32768 + (h)*16384 + tid*16 + 8192); \
} while (0)

#define STAGE_B(tile, h, buf) do {                                          \
  GL16(bptr##h + (tile) * 64,            65536 + (buf)*32768 + (h)*16384 + tid*16); \
  GL16(bptr##h + 64*K_IN + (tile) * 64,  65536 + (buf)*32768 + (h)*16384 + tid*16 + 8192); \
} while (0)

#define LOAD_A2(buf, i0) do {                                               \
  const char* ap_ = ldsc + (buf)*32768 + aoff + (i0)*2048;                  \
  afr[0][0] = *(const bf16x8*)(ap_ + col0);                                 \
  afr[0][1] = *(const bf16x8*)(ap_ + col1);                                 \
  afr[1][0] = *(const bf16x8*)(ap_ + 2048 + col0);                          \
  afr[1][1] = *(const bf16x8*)(ap_ + 2048 + col1);                          \
} while (0)

#define LOAD_B(buf) do {                                                    \
  const char* bp_ = ldsc + (buf)*32768 + boff;                              \
  _Pragma("unroll")                                                         \
  for (int j = 0; j < 4; ++j) {                                             \
    bfr[j][0] = *(const bf16x8*)(bp_ + j*2048 + col0);                      \
    bfr[j][1] = *(const bf16x8*)(bp_ + j*2048 + col1);                      \
  }                                                                         \
} while (0)

#define MFMA16(I0) do {                                                     \
  __builtin_amdgcn_s_setprio(1);                                            \
  _Pragma("unroll")                                                         \
  for (int kk = 0; kk < 2; ++kk)                                            \
    _Pragma("unroll")                                                       \
    for (int j = 0; j < 4; ++j) {                                           \
      acc[(I0)][j]     = __builtin_amdgcn_mfma_f32_16x16x32_bf16(           \
          afr[0][kk], bfr[j][kk], acc[(I0)][j], 0, 0, 0);                   \
      acc[(I0) + 1][j] = __builtin_amdgcn_mfma_f32_16x16x32_bf16(           \
          afr[1][kk], bfr[j][kk], acc[(I0) + 1][j], 0, 0, 0);               \
    }                                                                       \
  __builtin_amdgcn_s_setprio(0);                                            \
} while (0)

#define BAR()        __builtin_amdgcn_s_barrier()
#define WAIT_LGKM0() asm volatile("s_waitcnt lgkmcnt(0)" ::: "memory")
#define WAIT_VM6()   asm volatile("s_waitcnt vmcnt(6)" ::: "memory")

__global__ __launch_bounds__(512, 2) void gemm_bf16_256(
    const __bf16* __restrict__ A,   // [M][K]
    const __bf16* __restrict__ B,   // [N][K]
    const float* __restrict__ scale,
    const float* __restrict__ bias,
    float* __restrict__ C)          // [M][N]
{
  extern __shared__ char ldsc[];    // 131072 B

  const int tid  = threadIdx.x;
  const int lane = tid & 63;
  const int wid  = tid >> 6;
  const int wm = wid >> 2;          // 0..1 (M)
  const int wn = wid & 3;           // 0..3 (N)
  const int r = lane & 15;          // frag row (m for A, n for B)
  const int q = lane >> 4;          // k-quad

  // T1: XCD-aware swizzle; nwg = 43*32 = 1376 = 8*172 (divisible, bijective)
  const int bid = blockIdx.x;
  const int wg  = (bid & 7) * 172 + (bid >> 3);
  const int bx  = wg % 43;          // N tile
  const int by  = wg / 43;          // M tile
  const long long bm = (long long)by * 256;
  const long long bn = (long long)bx * 256;

  // staging map: chunk c = tid (+512); row = c>>3, col16 = (c&7) ^ (row&7)
  // (inverse-swizzled SOURCE so linear LDS dest + swizzled read round-trips)
  const int srow = tid >> 3;                       // 0..63 (second load: +64)
  const int scol = ((tid & 7) ^ (srow & 7)) << 3;  // bf16 elems; same for +64 row
  const __bf16* aptr0 = A + (bm + srow) * K_IN + scol;
  const __bf16* aptr1 = A + (bm + 128 + srow) * K_IN + scol;
  const __bf16* bptr0 = B + (bn + srow) * K_IN + scol;
  const __bf16* bptr1 = B + (bn + 128 + srow) * K_IN + scol;

  // ds_read addressing (swizzled): addr = base + row*128 + ((kk*64+q*16)^((r&7)<<4))
  const int swz  = (r & 7) << 4;
  const int col0 = (q * 16) ^ swz;
  const int col1 = col0 ^ 64;
  const int aoff = wm * 16384 + r * 128;
  const int boff = 65536 + (wn >> 1) * 16384 + ((wn & 1) * 64 + r) * 128;

  f32x4  acc[8][4] = {};
  bf16x8 afr[2][2], bfr[4][2];

  // ---- prologue: tile0 (A0,A1,B0,B1 -> buf0), tile1 (B0,B1,A0 -> buf1) ----
  STAGE_A(0, 0, 0); STAGE_A(0, 1, 0); STAGE_B(0, 0, 0); STAGE_B(0, 1, 0);
  STAGE_B(1, 0, 1); STAGE_B(1, 1, 1); STAGE_A(1, 0, 1);
  WAIT_VM6();                      // 14 issued, oldest 8 (= all of tile0) landed
  BAR();

#pragma unroll 1
  for (int it = 0; it < 64; it += 2) {
    const int t1 = (it + 1) & 63, t2 = (it + 2) & 63, t3 = (it + 3) & 63;
    // ---- P1 (buf0): B all + A i0-1; stage A-h1(t1)->buf1
    LOAD_B(0); LOAD_A2(0, 0);
    STAGE_A(t1, 1, 1);
    BAR(); WAIT_LGKM0();
    MFMA16(0);
    BAR();
    // ---- P2: A i2-3; stage B-h0(t2)->buf0 (buf0 B fully read at P1)
    LOAD_A2(0, 2);
    STAGE_B(t2, 0, 0);
    BAR(); WAIT_LGKM0();
    MFMA16(2);
    BAR();
    // ---- P3: A i4-5; stage B-h1(t2)->buf0
    LOAD_A2(0, 4);
    STAGE_B(t2, 1, 0);
    BAR(); WAIT_LGKM0();
    MFMA16(4);
    BAR();
    // ---- P4: A i6-7; stage A-h0(t2)->buf0 (rows 0-63 read by P2)
    LOAD_A2(0, 6);
    STAGE_A(t2, 0, 0);
    BAR(); WAIT_LGKM0();
    MFMA16(6);
    WAIT_VM6();                    // oldest 4 of 7 = tile t1 complete
    BAR();
    // ---- P5 (buf1): B all + A i0-1; stage A-h1(t2)->buf0
    LOAD_B(1); LOAD_A2(1, 0);
    STAGE_A(t2, 1, 0);
    BAR(); WAIT_LGKM0();
    MFMA16(0);
    BAR();
    // ---- P6: stage B-h0(t3)->buf1 (buf1 B fully read at P5)
    LOAD_A2(1, 2);
    STAGE_B(t3, 0, 1);
    BAR(); WAIT_LGKM0();
    MFMA16(2);
    BAR();
    // ---- P7
    LOAD_A2(1, 4);
    STAGE_B(t3, 1, 1);
    BAR(); WAIT_LGKM0();
    MFMA16(4);
    BAR();
    // ---- P8: stage A-h0(t3)->buf1 (rows 0-63 read by P6)
    LOAD_A2(1, 6);
    STAGE_A(t3, 0, 1);
    BAR(); WAIT_LGKM0();
    MFMA16(6);
    WAIT_VM6();                    // oldest 4 of 7 = tile t2 complete
    BAR();
  }

  // ---- epilogue: C/D layout col=lane&15, row=(lane>>4)*4+reg [m89-verified]
  const long long colg = bn + wn * 64 + r;
  const float* sc = scale + colg;
  const float* bi = bias + colg;
  float* Cb = C + (bm + wm * 128 + q * 4) * (long long)N_OUT + colg;
#pragma unroll
  for (int j = 0; j < 4; ++j) {
    const float s  = sc[j * 16];
    const float bb = bi[j * 16];
#pragma unroll
    for (int i = 0; i < 8; ++i) {
      float* cp = Cb + (long long)(i * 16) * N_OUT + j * 16;
#pragma unroll
      for (int e = 0; e < 4; ++e)
        cp[(long long)e * N_OUT] = acc[i][j][e] * s + bb;
    }
  }
}

// ---- fallback: previous verified 128x128 m97-style kernel (static 16KB LDS) ----
__global__ __launch_bounds__(256) void gemm_bf16_bt(
    const __bf16* __restrict__ A, const __bf16* __restrict__ B,
    const float* __restrict__ scale, const float* __restrict__ bias,
    float* __restrict__ C) {
  __shared__ __align__(16) __bf16 As[128 * 32];
  __shared__ __align__(16) __bf16 Bs[128 * 32];
  const int tid = threadIdx.x;
  const int lane = tid & 63;
  const int wave = tid >> 6;
  const long long bm = (long long)blockIdx.y * 128;
  const long long bn = (long long)blockIdx.x * 128;
  const int wm = (wave >> 1) * 64, wnn = (wave & 1) * 64;
  const int lr = lane & 15, lk = (lane >> 4) * 8;
  const int srow = tid >> 2, scol = (tid & 3) * 8;
  const __bf16* a0 = A + (bm + srow) * K_IN + scol;
  const __bf16* a1 = A + (bm + srow + 64) * K_IN + scol;
  const __bf16* b0 = B + (bn + srow) * K_IN + scol;
  const __bf16* b1 = B + (bn + srow + 64) * K_IN + scol;
  f32x4 acc[4][4] = {};
  for (int k0 = 0; k0 < K_IN; k0 += 32) {
    __builtin_amdgcn_global_load_lds((const __attribute__((address_space(1))) void*)(a0 + k0),
        (__attribute__((address_space(3))) void*)(As + tid * 8), 16, 0, 0);
    __builtin_amdgcn_global_load_lds((const __attribute__((address_space(1))) void*)(a1 + k0),
        (__attribute__((address_space(3))) void*)(As + 2048 + tid * 8), 16, 0, 0);
    __builtin_amdgcn_global_load_lds((const __attribute__((address_space(1))) void*)(b0 + k0),
        (__attribute__((address_space(3))) void*)(Bs + tid * 8), 16, 0, 0);
    __builtin_amdgcn_global_load_lds((const __attribute__((address_space(1))) void*)(b1 + k0),
        (__attribute__((address_space(3))) void*)(Bs + 2048 + tid * 8), 16, 0, 0);
    __syncthreads();
    bf16x8 af[4], bfv[4];
#pragma unroll
    for (int i = 0; i < 4; ++i) af[i] = *(const bf16x8*)(As + (wm + i * 16 + lr) * 32 + lk);
#pragma unroll
    for (int j = 0; j < 4; ++j) bfv[j] = *(const bf16x8*)(Bs + (wnn + j * 16 + lr) * 32 + lk);
#pragma unroll
    for (int i = 0; i < 4; ++i)
#pragma unroll
      for (int j = 0; j < 4; ++j)
        acc[i][j] = __builtin_amdgcn_mfma_f32_16x16x32_bf16(af[i], bfv[j], acc[i][j], 0, 0, 0);
    __syncthreads();
  }
  const int quad = lane >> 4;
#pragma unroll
  for (int j = 0; j < 4; ++j) {
    const long long col = bn + wnn + j * 16 + lr;
    const float s = scale[col], bb = bias[col];
#pragma unroll
    for (int i = 0; i < 4; ++i) {
      const long long row0 = bm + wm + i * 16 + quad * 4;
#pragma unroll
      for (int rr = 0; rr < 4; ++rr)
        C[(row0 + rr) * N_OUT + col] = acc[i][j][rr] * s + bb;
    }
  }
}

// ---- safety-net fallback if ws_size is too small (slow but correct) ----
__global__ void naive_qlinear(const float* __restrict__ in, const int* __restrict__ w,
                              const float* __restrict__ scale, const float* __restrict__ bias,
                              float* __restrict__ out) {
  long long total = (long long)M_TOK * N_OUT;
  for (long long idx = (long long)blockIdx.x * blockDim.x + threadIdx.x;
       idx < total; idx += (long long)gridDim.x * blockDim.x) {
    int t = (int)(idx / N_OUT), o = (int)(idx % N_OUT);
    const float* ip = in + (long long)t * K_IN;
    const int* wp = w + (long long)o * K_IN;
    float acc = 0.f;
    for (int k = 0; k < K_IN; ++k) acc += ip[k] * (float)wp[k];
    out[idx] = acc * scale[o] + bias[o];
  }
}

extern "C" void kernel_launch(void* const* d_in, const int* in_sizes, int n_in,
                              void* d_out, int out_size, void* d_ws, size_t ws_size,
                              hipStream_t stream) {
  const float* input  = (const float*)d_in[0];
  const int*   qw     = (const int*)d_in[1];
  const float* wscale = (const float*)d_in[2];
  const float* wbias  = (const float*)d_in[3];
  float* out = (float*)d_out;

  const size_t a_elems = (size_t)M_TOK * K_IN;   // 33,554,432
  const size_t b_elems = (size_t)N_OUT * K_IN;   // 45,088,768
  const size_t need = (a_elems + b_elems) * sizeof(unsigned short); // ~157 MB

  if (ws_size < need) {
    naive_qlinear<<<8192, 256, 0, stream>>>(input, qw, wscale, wbias, out);
    return;
  }

  // one-time opt-in to 128 KiB dynamic LDS for the 8-phase kernel
  static int use256 = -1;
  if (use256 < 0) {
    use256 = (hipFuncSetAttribute((const void*)gemm_bf16_256,
                                  hipFuncAttributeMaxDynamicSharedMemorySize,
                                  131072) == hipSuccess) ? 1 : 0;
  }

  unsigned short* Abf = (unsigned short*)d_ws;
  unsigned short* Bbf = Abf + a_elems;

  const int na8 = (int)(a_elems / 8);   // 4,194,304
  const int nb8 = (int)(b_elems / 8);   // 5,636,096
  cvt_f32_to_bf16<<<(na8 + 255) / 256, 256, 0, stream>>>(
      (const float4*)input, (u16x8*)Abf, na8);
  cvt_i32_to_bf16<<<(nb8 + 255) / 256, 256, 0, stream>>>(
      (const int4*)qw, (u16x8*)Bbf, nb8);

  if (use256) {
    gemm_bf16_256<<<dim3((N_OUT / 256) * (M_TOK / 256)), 512, 131072, stream>>>(
        (const __bf16*)Abf, (const __bf16*)Bbf, wscale, wbias, out);
  } else {
    gemm_bf16_bt<<<dim3(N_OUT / 128, M_TOK / 128), 256, 0, stream>>>(
        (const __bf16*)Abf, (const __bf16*)Bbf, wscale, wbias, out);
  }
}

// Round 2
// 1084.467 us; speedup vs baseline: 1.3605x; 1.0369x over previous
//
#include <hip/hip_runtime.h>
#include <hip/hip_bf16.h>

#define M_TOK 8192
#define K_IN  4096
#define N_OUT 11008

typedef __bf16 bf16x8 __attribute__((ext_vector_type(8)));
typedef float  f32x4  __attribute__((ext_vector_type(4)));
typedef int    i32x4  __attribute__((ext_vector_type(4)));
typedef unsigned short u16x8 __attribute__((ext_vector_type(8)));

__device__ __forceinline__ unsigned short f2bf_rne(float f) {
  unsigned int u = __float_as_uint(f);
  u += 0x7FFFu + ((u >> 16) & 1u);   // round-to-nearest-even
  return (unsigned short)(u >> 16);
}

// ---- fused conversion kernel (memory-bound): 32B nt-load / 16B store ----
// Inputs are read-once -> nontemporal loads keep the bf16 outputs (which the
// GEMM re-reads) resident in L2/L3 instead of being evicted by the f32/i32.
__global__ __launch_bounds__(256) void cvt_fused(
    const f32x4* __restrict__ af32, const i32x4* __restrict__ bi32,
    u16x8* __restrict__ aout, u16x8* __restrict__ bout, int na8, int nb8) {
  int i = blockIdx.x * blockDim.x + threadIdx.x;
  if (i < na8) {
    f32x4 a = __builtin_nontemporal_load(af32 + 2 * i);
    f32x4 b = __builtin_nontemporal_load(af32 + 2 * i + 1);
    u16x8 o;
    o[0] = f2bf_rne(a[0]); o[1] = f2bf_rne(a[1]); o[2] = f2bf_rne(a[2]); o[3] = f2bf_rne(a[3]);
    o[4] = f2bf_rne(b[0]); o[5] = f2bf_rne(b[1]); o[6] = f2bf_rne(b[2]); o[7] = f2bf_rne(b[3]);
    aout[i] = o;
  } else {
    int j = i - na8;
    if (j < nb8) {
      i32x4 a = __builtin_nontemporal_load(bi32 + 2 * j);
      i32x4 b = __builtin_nontemporal_load(bi32 + 2 * j + 1);
      u16x8 o;  // values {0,1,2} -> exact in bf16
      o[0] = f2bf_rne((float)a[0]); o[1] = f2bf_rne((float)a[1]);
      o[2] = f2bf_rne((float)a[2]); o[3] = f2bf_rne((float)a[3]);
      o[4] = f2bf_rne((float)b[0]); o[5] = f2bf_rne((float)b[1]);
      o[6] = f2bf_rne((float)b[2]); o[7] = f2bf_rne((float)b[3]);
      bout[j] = o;
    }
  }
}

// ============================================================================
// 256x256 8-phase bf16 NT GEMM (T1 XCD-swizzle + T2 LDS XOR-swizzle +
// T3/T4 8-phase counted-vmcnt + T5 setprio), per cdna_hip_programming.md §5.
// C[t][o] = sum_k A[t][k]*B[o][k]; epilogue *scale[o]+bias[o].
// This round: nontemporal C stores (no-allocate) so the 360MB C stream stops
// evicting the A/B bf16 panels (157MB, fits 256MiB L3) -> lower load latency,
// lower HBM re-fetch. Plus lgkmcnt(8) early drain in the 12-ds_read phases.
// ============================================================================

#define GL16(gp, loff)                                                      \
  __builtin_amdgcn_global_load_lds(                                        \
      (const __attribute__((address_space(1))) void*)(gp),                 \
      (__attribute__((address_space(3))) void*)(ldsc + (loff)), 16, 0, 0)

#define STAGE_A(tile, h, buf) do {                                          \
  GL16(aptr##h + (tile) * 64,            (buf)*32768 + (h)*16384 + tid*16); \
  GL16(aptr##h + 64*K_IN + (tile) * 64,  (buf)*32768 + (h)*16384 + tid*16 + 8192); \
} while (0)

#define STAGE_B(tile, h, buf) do {                                          \
  GL16(bptr##h + (tile) * 64,            65536 + (buf)*32768 + (h)*16384 + tid*16); \
  GL16(bptr##h + 64*K_IN + (tile) * 64,  65536 + (buf)*32768 + (h)*16384 + tid*16 + 8192); \
} while (0)

#define LOAD_A2(buf, i0) do {                                               \
  const char* ap_ = ldsc + (buf)*32768 + aoff + (i0)*2048;                  \
  afr[0][0] = *(const bf16x8*)(ap_ + col0);                                 \
  afr[0][1] = *(const bf16x8*)(ap_ + col1);                                 \
  afr[1][0] = *(const bf16x8*)(ap_ + 2048 + col0);                          \
  afr[1][1] = *(const bf16x8*)(ap_ + 2048 + col1);                          \
} while (0)

#define LOAD_B(buf) do {                                                    \
  const char* bp_ = ldsc + (buf)*32768 + boff;                              \
  _Pragma("unroll")                                                         \
  for (int j = 0; j < 4; ++j) {                                             \
    bfr[j][0] = *(const bf16x8*)(bp_ + j*2048 + col0);                      \
    bfr[j][1] = *(const bf16x8*)(bp_ + j*2048 + col1);                      \
  }                                                                         \
} while (0)

#define MFMA16(I0) do {                                                     \
  __builtin_amdgcn_s_setprio(1);                                            \
  _Pragma("unroll")                                                         \
  for (int kk = 0; kk < 2; ++kk)                                            \
    _Pragma("unroll")                                                       \
    for (int j = 0; j < 4; ++j) {                                           \
      acc[(I0)][j]     = __builtin_amdgcn_mfma_f32_16x16x32_bf16(           \
          afr[0][kk], bfr[j][kk], acc[(I0)][j], 0, 0, 0);                   \
      acc[(I0) + 1][j] = __builtin_amdgcn_mfma_f32_16x16x32_bf16(           \
          afr[1][kk], bfr[j][kk], acc[(I0) + 1][j], 0, 0, 0);               \
    }                                                                       \
  __builtin_amdgcn_s_setprio(0);                                            \
} while (0)

#define BAR()        __builtin_amdgcn_s_barrier()
#define WAIT_LGKM0() asm volatile("s_waitcnt lgkmcnt(0)" ::: "memory")
#define WAIT_LGKM8() asm volatile("s_waitcnt lgkmcnt(8)" ::: "memory")
#define WAIT_VM6()   asm volatile("s_waitcnt vmcnt(6)" ::: "memory")

__global__ __launch_bounds__(512, 2) void gemm_bf16_256(
    const __bf16* __restrict__ A,   // [M][K]
    const __bf16* __restrict__ B,   // [N][K]
    const float* __restrict__ scale,
    const float* __restrict__ bias,
    float* __restrict__ C)          // [M][N]
{
  extern __shared__ char ldsc[];    // 131072 B

  const int tid  = threadIdx.x;
  const int lane = tid & 63;
  const int wid  = tid >> 6;
  const int wm = wid >> 2;          // 0..1 (M)
  const int wn = wid & 3;           // 0..3 (N)
  const int r = lane & 15;          // frag row (m for A, n for B)
  const int q = lane >> 4;          // k-quad

  // T1: XCD-aware swizzle; nwg = 43*32 = 1376 = 8*172 (divisible, bijective)
  const int bid = blockIdx.x;
  const int wg  = (bid & 7) * 172 + (bid >> 3);
  const int bx  = wg % 43;          // N tile
  const int by  = wg / 43;          // M tile
  const long long bm = (long long)by * 256;
  const long long bn = (long long)bx * 256;

  // staging map: chunk c = tid (+512); row = c>>3, col16 = (c&7) ^ (row&7)
  // (inverse-swizzled SOURCE so linear LDS dest + swizzled read round-trips)
  const int srow = tid >> 3;                       // 0..63 (second load: +64)
  const int scol = ((tid & 7) ^ (srow & 7)) << 3;  // bf16 elems; same for +64 row
  const __bf16* aptr0 = A + (bm + srow) * K_IN + scol;
  const __bf16* aptr1 = A + (bm + 128 + srow) * K_IN + scol;
  const __bf16* bptr0 = B + (bn + srow) * K_IN + scol;
  const __bf16* bptr1 = B + (bn + 128 + srow) * K_IN + scol;

  // ds_read addressing (swizzled): addr = base + row*128 + ((kk*64+q*16)^((r&7)<<4))
  const int swz  = (r & 7) << 4;
  const int col0 = (q * 16) ^ swz;
  const int col1 = col0 ^ 64;
  const int aoff = wm * 16384 + r * 128;
  const int boff = 65536 + (wn >> 1) * 16384 + ((wn & 1) * 64 + r) * 128;

  f32x4  acc[8][4] = {};
  bf16x8 afr[2][2], bfr[4][2];

  // ---- prologue: tile0 (A0,A1,B0,B1 -> buf0), tile1 (B0,B1,A0 -> buf1) ----
  STAGE_A(0, 0, 0); STAGE_A(0, 1, 0); STAGE_B(0, 0, 0); STAGE_B(0, 1, 0);
  STAGE_B(1, 0, 1); STAGE_B(1, 1, 1); STAGE_A(1, 0, 1);
  WAIT_VM6();                      // 14 issued, oldest 8 (= all of tile0) landed
  BAR();

#pragma unroll 1
  for (int it = 0; it < 64; it += 2) {
    const int t1 = (it + 1) & 63, t2 = (it + 2) & 63, t3 = (it + 3) & 63;
    // ---- P1 (buf0): B all + A i0-1; stage A-h1(t1)->buf1
    LOAD_B(0); LOAD_A2(0, 0);
    STAGE_A(t1, 1, 1);
    WAIT_LGKM8();                  // early drain (12 ds_reads in flight)
    BAR(); WAIT_LGKM0();
    MFMA16(0);
    BAR();
    // ---- P2: A i2-3; stage B-h0(t2)->buf0 (buf0 B fully read at P1)
    LOAD_A2(0, 2);
    STAGE_B(t2, 0, 0);
    BAR(); WAIT_LGKM0();
    MFMA16(2);
    BAR();
    // ---- P3: A i4-5; stage B-h1(t2)->buf0
    LOAD_A2(0, 4);
    STAGE_B(t2, 1, 0);
    BAR(); WAIT_LGKM0();
    MFMA16(4);
    BAR();
    // ---- P4: A i6-7; stage A-h0(t2)->buf0 (rows 0-63 read by P2)
    LOAD_A2(0, 6);
    STAGE_A(t2, 0, 0);
    BAR(); WAIT_LGKM0();
    MFMA16(6);
    WAIT_VM6();                    // oldest 4 of 7 = tile t1 complete
    BAR();
    // ---- P5 (buf1): B all + A i0-1; stage A-h1(t2)->buf0
    LOAD_B(1); LOAD_A2(1, 0);
    STAGE_A(t2, 1, 0);
    WAIT_LGKM8();
    BAR(); WAIT_LGKM0();
    MFMA16(0);
    BAR();
    // ---- P6: stage B-h0(t3)->buf1 (buf1 B fully read at P5)
    LOAD_A2(1, 2);
    STAGE_B(t3, 0, 1);
    BAR(); WAIT_LGKM0();
    MFMA16(2);
    BAR();
    // ---- P7
    LOAD_A2(1, 4);
    STAGE_B(t3, 1, 1);
    BAR(); WAIT_LGKM0();
    MFMA16(4);
    BAR();
    // ---- P8: stage A-h0(t3)->buf1 (rows 0-63 read by P6)
    LOAD_A2(1, 6);
    STAGE_A(t3, 0, 1);
    BAR(); WAIT_LGKM0();
    MFMA16(6);
    WAIT_VM6();                    // oldest 4 of 7 = tile t2 complete
    BAR();
  }

  // ---- epilogue: C/D layout col=lane&15, row=(lane>>4)*4+reg [m89-verified]
  // Nontemporal stores: C is write-once/streaming; no-allocate keeps the
  // A/B bf16 panels resident in L3 for all other blocks.
  const long long colg = bn + wn * 64 + r;
  const float* sc = scale + colg;
  const float* bi = bias + colg;
  float* Cb = C + (bm + wm * 128 + q * 4) * (long long)N_OUT + colg;
#pragma unroll
  for (int j = 0; j < 4; ++j) {
    const float s  = sc[j * 16];
    const float bb = bi[j * 16];
#pragma unroll
    for (int i = 0; i < 8; ++i) {
      float* cp = Cb + (long long)(i * 16) * N_OUT + j * 16;
#pragma unroll
      for (int e = 0; e < 4; ++e)
        __builtin_nontemporal_store(acc[i][j][e] * s + bb,
                                    cp + (long long)e * N_OUT);
    }
  }
}

// ---- fallback: previous verified 128x128 m97-style kernel (static 16KB LDS) ----
__global__ __launch_bounds__(256) void gemm_bf16_bt(
    const __bf16* __restrict__ A, const __bf16* __restrict__ B,
    const float* __restrict__ scale, const float* __restrict__ bias,
    float* __restrict__ C) {
  __shared__ __align__(16) __bf16 As[128 * 32];
  __shared__ __align__(16) __bf16 Bs[128 * 32];
  const int tid = threadIdx.x;
  const int lane = tid & 63;
  const int wave = tid >> 6;
  const long long bm = (long long)blockIdx.y * 128;
  const long long bn = (long long)blockIdx.x * 128;
  const int wm = (wave >> 1) * 64, wnn = (wave & 1) * 64;
  const int lr = lane & 15, lk = (lane >> 4) * 8;
  const int srow = tid >> 2, scol = (tid & 3) * 8;
  const __bf16* a0 = A + (bm + srow) * K_IN + scol;
  const __bf16* a1 = A + (bm + srow + 64) * K_IN + scol;
  const __bf16* b0 = B + (bn + srow) * K_IN + scol;
  const __bf16* b1 = B + (bn + srow + 64) * K_IN + scol;
  f32x4 acc[4][4] = {};
  for (int k0 = 0; k0 < K_IN; k0 += 32) {
    __builtin_amdgcn_global_load_lds((const __attribute__((address_space(1))) void*)(a0 + k0),
        (__attribute__((address_space(3))) void*)(As + tid * 8), 16, 0, 0);
    __builtin_amdgcn_global_load_lds((const __attribute__((address_space(1))) void*)(a1 + k0),
        (__attribute__((address_space(3))) void*)(As + 2048 + tid * 8), 16, 0, 0);
    __builtin_amdgcn_global_load_lds((const __attribute__((address_space(1))) void*)(b0 + k0),
        (__attribute__((address_space(3))) void*)(Bs + tid * 8), 16, 0, 0);
    __builtin_amdgcn_global_load_lds((const __attribute__((address_space(1))) void*)(b1 + k0),
        (__attribute__((address_space(3))) void*)(Bs + 2048 + tid * 8), 16, 0, 0);
    __syncthreads();
    bf16x8 af[4], bfv[4];
#pragma unroll
    for (int i = 0; i < 4; ++i) af[i] = *(const bf16x8*)(As + (wm + i * 16 + lr) * 32 + lk);
#pragma unroll
    for (int j = 0; j < 4; ++j) bfv[j] = *(const bf16x8*)(Bs + (wnn + j * 16 + lr) * 32 + lk);
#pragma unroll
    for (int i = 0; i < 4; ++i)
#pragma unroll
      for (int j = 0; j < 4; ++j)
        acc[i][j] = __builtin_amdgcn_mfma_f32_16x16x32_bf16(af[i], bfv[j], acc[i][j], 0, 0, 0);
    __syncthreads();
  }
  const int quad = lane >> 4;
#pragma unroll
  for (int j = 0; j < 4; ++j) {
    const long long col = bn + wnn + j * 16 + lr;
    const float s = scale[col], bb = bias[col];
#pragma unroll
    for (int i = 0; i < 4; ++i) {
      const long long row0 = bm + wm + i * 16 + quad * 4;
#pragma unroll
      for (int rr = 0; rr < 4; ++rr)
        C[(row0 + rr) * N_OUT + col] = acc[i][j][rr] * s + bb;
    }
  }
}

// ---- safety-net fallback if ws_size is too small (slow but correct) ----
__global__ void naive_qlinear(const float* __restrict__ in, const int* __restrict__ w,
                              const float* __restrict__ scale, const float* __restrict__ bias,
                              float* __restrict__ out) {
  long long total = (long long)M_TOK * N_OUT;
  for (long long idx = (long long)blockIdx.x * blockDim.x + threadIdx.x;
       idx < total; idx += (long long)gridDim.x * blockDim.x) {
    int t = (int)(idx / N_OUT), o = (int)(idx % N_OUT);
    const float* ip = in + (long long)t * K_IN;
    const int* wp = w + (long long)o * K_IN;
    float acc = 0.f;
    for (int k = 0; k < K_IN; ++k) acc += ip[k] * (float)wp[k];
    out[idx] = acc * scale[o] + bias[o];
  }
}

extern "C" void kernel_launch(void* const* d_in, const int* in_sizes, int n_in,
                              void* d_out, int out_size, void* d_ws, size_t ws_size,
                              hipStream_t stream) {
  const float* input  = (const float*)d_in[0];
  const int*   qw     = (const int*)d_in[1];
  const float* wscale = (const float*)d_in[2];
  const float* wbias  = (const float*)d_in[3];
  float* out = (float*)d_out;

  const size_t a_elems = (size_t)M_TOK * K_IN;   // 33,554,432
  const size_t b_elems = (size_t)N_OUT * K_IN;   // 45,088,768
  const size_t need = (a_elems + b_elems) * sizeof(unsigned short); // ~157 MB

  if (ws_size < need) {
    naive_qlinear<<<8192, 256, 0, stream>>>(input, qw, wscale, wbias, out);
    return;
  }

  // one-time opt-in to 128 KiB dynamic LDS for the 8-phase kernel
  static int use256 = -1;
  if (use256 < 0) {
    use256 = (hipFuncSetAttribute((const void*)gemm_bf16_256,
                                  hipFuncAttributeMaxDynamicSharedMemorySize,
                                  131072) == hipSuccess) ? 1 : 0;
  }

  unsigned short* Abf = (unsigned short*)d_ws;
  unsigned short* Bbf = Abf + a_elems;

  const int na8 = (int)(a_elems / 8);   // 4,194,304 (divisible by 256)
  const int nb8 = (int)(b_elems / 8);   // 5,636,096
  const int ntot = na8 + nb8;
  cvt_fused<<<(ntot + 255) / 256, 256, 0, stream>>>(
      (const f32x4*)input, (const i32x4*)qw, (u16x8*)Abf, (u16x8*)Bbf, na8, nb8);

  if (use256) {
    gemm_bf16_256<<<dim3((N_OUT / 256) * (M_TOK / 256)), 512, 131072, stream>>>(
        (const __bf16*)Abf, (const __bf16*)Bbf, wscale, wbias, out);
  } else {
    gemm_bf16_bt<<<dim3(N_OUT / 128, M_TOK / 128), 256, 0, stream>>>(
        (const __bf16*)Abf, (const __bf16*)Bbf, wscale, wbias, out);
  }
}